// Round 7
// baseline (403.647 us; speedup 1.0000x reference)
//
#include <hip/hip_runtime.h>
#include <hip/hip_bf16.h>

// RGCN forward, MI355X. N=100000, E=400000, IN=OUT=256, R=200, B=32.
// Tier A: prep1{wgen|slwpk|hist+feat} -> prep2{etype-scan|deg-blocksums} ->
// prep3{deg-scan} -> prep4{scatter: gsrc/gdst/ginv/dlist} -> selfA GEMM ->
// pipelined edge GEMM (NT=4 tiles/block, global_load_lds double-buffer,
// gather t+1 in flight under MFMA t) -> LDS-free aggregate.

#define NN 100000
#define EE 400000
#define RR 200
#define BB 32
#define MAXTILES 6464   // >= E/64 + R ; divisible by 32
#define NT 4
#define EGRID (MAXTILES / NT)   // 1616
#define EQX (EGRID / 8)         // 202
#define SCHUNK 2048
#define NSCAN ((NN + 255) / 256) // 391

typedef __attribute__((ext_vector_type(8))) short short8v;   // 8 x bf16 (16B)
typedef __attribute__((ext_vector_type(4))) float f32x4;

__device__ __forceinline__ unsigned short f2bf(float f) {
  unsigned u = __float_as_uint(f);
  u += 0x7FFF + ((u >> 16) & 1);          // RNE
  return (unsigned short)(u >> 16);
}
__device__ __forceinline__ float bf2f(unsigned short h) {
  return __uint_as_float(((unsigned)h) << 16);
}

// async 16B/lane global->LDS. lds dest must be wave-uniform base (HW adds
// lane*16); swizzle is pre-applied on the per-lane GLOBAL address (m173).
typedef __attribute__((address_space(1))) void gas_void;
typedef __attribute__((address_space(3))) void las_void;
__device__ __forceinline__ void glds16(const void* g, void* l) {
  __builtin_amdgcn_global_load_lds((gas_void*)g, (las_void*)l, 16, 0, 0);
}

// ---------------------------------------------------------------------------
// prep1: blocks [0,800): wgen (L2-blocked W_r pack); [800,832): slwpk;
// [832,1344): etype hist + dst degree + (FEAT) f32->bf16 feature convert.
// W_pk layout per relation: [ct=16][kt=8][lane=64][j=8] bf16 where
//   value = W_r[k = kt*32 + (lane>>4)*8 + j][n = ct*16 + (lane&15)].
template <bool FEAT>
__global__ __launch_bounds__(256) void k_prep1(
    const float* __restrict__ basis, const float* __restrict__ coef,
    const float* __restrict__ slw, const int* __restrict__ etype,
    const int* __restrict__ dst, const float* __restrict__ in_feat,
    short* __restrict__ wpk, short* __restrict__ spk,
    int* __restrict__ hist, int* __restrict__ deg,
    unsigned short* __restrict__ featb) {
  __shared__ int lh[RR];
  int b = blockIdx.x, tid = threadIdx.x;
  if (b < 800) {                       // ---- wgen ----
    int ord = (b & 7) * 100 + (b >> 3);
    int rg = ord % 25;
    int pk8 = (ord / 25) * 256 + tid;
    int lane = pk8 & 63;
    int kt = (pk8 >> 6) & 7;
    int ct = pk8 >> 9;
    int n  = ct * 16 + (lane & 15);
    int k0 = kt * 32 + ((lane >> 4) << 3);
    float acc[8][8];
#pragma unroll
    for (int r = 0; r < 8; ++r)
#pragma unroll
      for (int j = 0; j < 8; ++j) acc[r][j] = 0.f;
    for (int bb = 0; bb < BB; ++bb) {
      float bas[8];
#pragma unroll
      for (int j = 0; j < 8; ++j) bas[j] = basis[bb * 65536 + (k0 + j) * 256 + n];
#pragma unroll
      for (int r = 0; r < 8; ++r) {
        float c = coef[(rg * 8 + r) * BB + bb];
#pragma unroll
        for (int j = 0; j < 8; ++j) acc[r][j] += c * bas[j];
      }
    }
#pragma unroll
    for (int r = 0; r < 8; ++r) {
      short8v v;
#pragma unroll
      for (int j = 0; j < 8; ++j) v[j] = (short)f2bf(acc[r][j]);
      *(short8v*)(wpk + (size_t)(rg * 8 + r) * 65536 + (size_t)pk8 * 8) = v;
    }
    return;
  }
  if (b < 832) {                       // ---- slwpk ----
    int t = (b - 800) * 256 + tid;
    int lane = t & 63;
    int kt = (t >> 6) & 7;
    int ct = t >> 9;
    int n  = ct * 16 + (lane & 15);
    int k0 = kt * 32 + ((lane >> 4) << 3);
    short8v v;
#pragma unroll
    for (int j = 0; j < 8; ++j) v[j] = (short)f2bf(slw[(k0 + j) * 256 + n]);
    *(short8v*)(spk + (size_t)t * 8) = v;
    return;
  }
  // ---- hist + deg + feat ----
  int hb = b - 832;                    // 512 blocks
  for (int i = tid; i < RR; i += 256) lh[i] = 0;
  __syncthreads();
  for (int e = hb * 256 + tid; e < EE; e += 512 * 256) {
    atomicAdd(&lh[etype[e]], 1);
    atomicAdd(&deg[dst[e]], 1);
  }
  if (FEAT) {
    const int total = NN * 64;         // float4 count
    for (int i = hb * 256 + tid; i < total; i += 512 * 256) {
      float4 v = ((const float4*)in_feat)[i];
      ushort4 h;
      h.x = f2bf(v.x); h.y = f2bf(v.y); h.z = f2bf(v.z); h.w = f2bf(v.w);
      ((ushort4*)featb)[i] = h;
    }
  }
  __syncthreads();
  for (int i = tid; i < RR; i += 256)
    if (lh[i]) atomicAdd(&hist[i], lh[i]);
}

// ---------------------------------------------------------------------------
// prep2: block 0: etype-bin scan -> cur + tdesc; blocks 1..391: deg block sums.
__global__ __launch_bounds__(256) void k_prep2(const int* __restrict__ hist,
                                               const int* __restrict__ deg,
                                               int* __restrict__ cur,
                                               int4* __restrict__ tdesc,
                                               int* __restrict__ bsum) {
  __shared__ int h[RR];
  __shared__ int off[RR];
  __shared__ int toff[RR];
  __shared__ int tot;
  __shared__ int ws4[4];
  int b = blockIdx.x, tid = threadIdx.x;
  if (b == 0) {
    for (int i = tid; i < RR; i += 256) h[i] = hist[i];
    __syncthreads();
    if (tid == 0) {
      int s = 0, ts = 0;
      for (int r = 0; r < RR; ++r) {
        off[r] = s; s += h[r];
        toff[r] = ts; ts += (h[r] + 63) >> 6;
      }
      tot = ts;
    }
    __syncthreads();
    if (tid < RR) {
      int r = tid, cnt = h[r], base = off[r], to = toff[r];
      cur[r] = base;
      int nt = (cnt + 63) >> 6;
      for (int t2 = 0; t2 < nt; ++t2)
        tdesc[to + t2] = make_int4(r, base + t2 * 64, min(64, cnt - t2 * 64), 0);
    }
    for (int i = tot + tid; i < MAXTILES; i += 256)
      tdesc[i] = make_int4(0, 0, 0, 0);
    return;
  }
  int i = (b - 1) * 256 + tid;
  int v = (i < NN) ? deg[i] : 0;
#pragma unroll
  for (int d = 32; d; d >>= 1) v += __shfl_down(v, d, 64);
  if ((tid & 63) == 0) ws4[tid >> 6] = v;
  __syncthreads();
  if (tid == 0) bsum[b - 1] = ws4[0] + ws4[1] + ws4[2] + ws4[3];
}

// prep3 (tier A): deg exclusive scan -> row_ptr/cur2; bsum prefix inline.
__global__ __launch_bounds__(256) void k_prep3(const int* __restrict__ deg,
                                               const int* __restrict__ bsum,
                                               int* __restrict__ row_ptr,
                                               int* __restrict__ cur2) {
  __shared__ int ws4[4];
  __shared__ int wo4[4];
  __shared__ int psum[4];
  int tid = threadIdx.x, b = blockIdx.x;
  int sp = 0;
  for (int i = tid; i < b; i += 256) sp += bsum[i];
#pragma unroll
  for (int d = 32; d; d >>= 1) sp += __shfl_down(sp, d, 64);
  if ((tid & 63) == 0) psum[tid >> 6] = sp;
  int i = b * 256 + tid;
  int v = (i < NN) ? deg[i] : 0;
  int x = v;
#pragma unroll
  for (int d = 1; d < 64; d <<= 1) {
    int y = __shfl_up(x, d, 64);
    if ((tid & 63) >= d) x += y;
  }
  if ((tid & 63) == 63) ws4[tid >> 6] = x;
  __syncthreads();
  if (tid == 0) {
    int s = 0;
    for (int w2 = 0; w2 < 4; ++w2) { wo4[w2] = s; s += ws4[w2]; }
    psum[0] = psum[0] + psum[1] + psum[2] + psum[3];
  }
  __syncthreads();
  int excl = x - v + wo4[tid >> 6] + psum[0];
  if (i < NN) { row_ptr[i] = excl; cur2[i] = excl; }
  if (i == 0 && b == 0) row_ptr[NN] = EE;
}

// prep4: counting-sort scatter; materializes per-position gsrc/gdst/ginv and
// (DL) dst-CSR value list.
template <bool DL>
__global__ __launch_bounds__(256) void k_prep4(const int* __restrict__ etype,
                                               const int* __restrict__ src,
                                               const int* __restrict__ dst,
                                               const int* __restrict__ deg,
                                               int* __restrict__ cur,
                                               int* __restrict__ gsrc,
                                               int* __restrict__ gdst,
                                               float* __restrict__ ginv,
                                               int* __restrict__ cur2,
                                               int* __restrict__ dlist) {
  __shared__ int lh[RR];
  __shared__ int lbase[RR];
  __shared__ int lcur[RR];
  int tid = threadIdx.x;
  int e0 = blockIdx.x * SCHUNK;
  for (int i = tid; i < RR; i += 256) lh[i] = 0;
  __syncthreads();
  for (int i = tid; i < SCHUNK; i += 256) {
    int e = e0 + i;
    if (e < EE) atomicAdd(&lh[etype[e]], 1);
  }
  __syncthreads();
  for (int i = tid; i < RR; i += 256) {
    int c = lh[i];
    lbase[i] = c ? atomicAdd(&cur[i], c) : 0;
    lcur[i] = 0;
  }
  __syncthreads();
  for (int i = tid; i < SCHUNK; i += 256) {
    int e = e0 + i;
    if (e < EE) {
      int et = etype[e];
      int s = lbase[et] + atomicAdd(&lcur[et], 1);
      int d = dst[e];
      gsrc[s] = src[e];
      gdst[s] = d;
      ginv[s] = 1.0f / (float)max(deg[d], 1);
      if (DL) {
        int pos = atomicAdd(&cur2[d], 1);
        dlist[pos] = s;
      }
    }
  }
}

// ---------------------------------------------------------------------------
// Tier A edge GEMM, pipelined: 512 threads (8 waves = 2x4), NT=4 tiles per
// block, double-buffered LDS filled by global_load_lds (swizzle applied on
// the per-lane GLOBAL address; LDS dest is wave-uniform + lane*16). Gather of
// tile t+1 is in flight under MFMA/epilogue of tile t. tdescs loaded once;
// srow/ginv prefetched 2 tiles ahead. acc[2][4] = 32 AGPR; no staging regs.
__global__ __launch_bounds__(512) void k_edge(
    const unsigned short* __restrict__ featb, const short* __restrict__ wpk,
    const int* __restrict__ gsrc, const float* __restrict__ ginv,
    const int4* __restrict__ tdesc, unsigned short* __restrict__ msg) {
  __shared__ __align__(16) char lA[2][32768];
  __shared__ float lL[2][64];
  int tid = threadIdx.x, wave = tid >> 6, lane = tid & 63;
  int l15 = lane & 15, lg = lane >> 4;
  int wm = wave >> 2, wc = wave & 3;
  int bid = blockIdx.x;
  int t0 = ((bid & 7) * EQX + (bid >> 3)) * NT;   // XCD-contiguous tile range
  int4 td[NT];
#pragma unroll
  for (int i = 0; i < NT; ++i) td[i] = tdesc[t0 + i];
  if (td[0].z <= 0) return;            // padding tiles are a suffix

  int pchk = tid & 31;                 // 16B chunk within row
  int prow[4];
#pragma unroll
  for (int u = 0; u < 4; ++u) prow[u] = u * 16 + (tid >> 5);

  // ---- prologue: meta(t0) -> glds(t0) -> meta(t0+1) ----
  int srn[4]; float gvn = 0.f;
  {
    int rs = td[0].y;
    int sr0[4]; float gv0 = 0.f;
#pragma unroll
    for (int u = 0; u < 4; ++u) sr0[u] = gsrc[min(rs + prow[u], EE - 1)];
    if (tid < 64) gv0 = ginv[min(rs + tid, EE - 1)];
#pragma unroll
    for (int u = 0; u < 4; ++u)
      glds16(featb + (size_t)sr0[u] * 256 + ((pchk ^ (prow[u] & 7)) << 3),
             &lA[0][u * 8192 + wave * 1024]);
    if (tid < 64) lL[0][tid] = gv0;
    int rs1 = td[1].y;
#pragma unroll
    for (int u = 0; u < 4; ++u) srn[u] = gsrc[min(rs1 + prow[u], EE - 1)];
    if (tid < 64) gvn = ginv[min(rs1 + tid, EE - 1)];
  }
  __syncthreads();                     // drains glds -> buf0 + lL0 ready

#pragma unroll
  for (int i = 0; i < NT; ++i) {
    const int cur = i & 1, nxt = cur ^ 1;
    int rows_c = td[i].z, r_c = td[i].x, rs_c = td[i].y;
    // stage tile i+1 (async, lands before next opening barrier)
    if (i + 1 < NT) {
      if (tid < 64) lL[nxt][tid] = gvn;
#pragma unroll
      for (int u = 0; u < 4; ++u)
        glds16(featb + (size_t)srn[u] * 256 + ((pchk ^ (prow[u] & 7)) << 3),
               &lA[nxt][u * 8192 + wave * 1024]);
    }
    // prefetch meta for tile i+2 (2 iterations of slack)
    int sr2[4]; float gv2 = 0.f;
    if (i + 2 < NT) {
      int rs = td[i + 2].y;
#pragma unroll
      for (int u = 0; u < 4; ++u) sr2[u] = gsrc[min(rs + prow[u], EE - 1)];
      if (tid < 64) gv2 = ginv[min(rs + tid, EE - 1)];
    }
    if (rows_c > 0) {
      f32x4 acc[2][4];
#pragma unroll
      for (int m = 0; m < 2; ++m)
#pragma unroll
        for (int c = 0; c < 4; ++c) acc[m][c] = (f32x4){0.f, 0.f, 0.f, 0.f};
      const short* bp = wpk + (size_t)r_c * 65536 +
                        (size_t)(wc * 4) * 4096 + (size_t)lane * 8;
#pragma unroll
      for (int kt = 0; kt < 8; ++kt) {
        short8v bfr[4], a2[2];
#pragma unroll
        for (int c = 0; c < 4; ++c)
          bfr[c] = *(const short8v*)(bp + c * 4096 + kt * 512);
#pragma unroll
        for (int m = 0; m < 2; ++m) {
          int row = wm * 32 + m * 16 + l15;
          a2[m] = *(const short8v*)(&lA[cur][0] +
                     ((row * 512 + kt * 64 + lg * 16) ^ ((row & 7) << 4)));
        }
#pragma unroll
        for (int m = 0; m < 2; ++m)
#pragma unroll
          for (int c = 0; c < 4; ++c)
            acc[m][c] = __builtin_amdgcn_mfma_f32_16x16x32_bf16(a2[m], bfr[c],
                                                                acc[m][c], 0, 0, 0);
      }
      __syncthreads();                 // all waves done reading lA[cur]
      // scale + repack bf16 via lA[cur]
#pragma unroll
      for (int m = 0; m < 2; ++m)
#pragma unroll
        for (int j = 0; j < 4; ++j) {
          int row = wm * 32 + m * 16 + lg * 4 + j;
          float inv = lL[cur][row];
          int rb = row * 512, sw = (row & 7) << 4;
#pragma unroll
          for (int c = 0; c < 4; ++c) {
            int col = wc * 64 + c * 16 + l15;
            *(unsigned short*)(&lA[cur][0] + ((rb + col * 2) ^ sw)) =
                f2bf(acc[m][c][j] * inv);
          }
        }
      __syncthreads();                 // repack visible
#pragma unroll
      for (int u = 0; u < 4; ++u) {
        int idx = u * 512 + tid;
        int row = idx >> 5, q = idx & 31;
        if (row < rows_c) {
          short8v vv = *(const short8v*)(&lA[cur][0] +
                          ((row * 512 + q * 16) ^ ((row & 7) << 4)));
          *(short8v*)(msg + (size_t)(rs_c + row) * 256 + q * 8) = vv;
        }
      }
    } else {
      __syncthreads();
      __syncthreads();
    }
#pragma unroll
    for (int u = 0; u < 4; ++u) srn[u] = sr2[u];
    gvn = gv2;
    __syncthreads();                   // closing: drains glds(t+1) + epilogue
  }
}

// ---------------------------------------------------------------------------
// Tier A self-loop GEMM: out[n] = featb[n] @ slw (f32 out, direct store).
__global__ __launch_bounds__(256) void k_selfA(const unsigned short* __restrict__ featb,
                                               const short* __restrict__ spk,
                                               float* __restrict__ out) {
  __shared__ __align__(16) char lA[32768];
  int tid = threadIdx.x, wave = tid >> 6, lane = tid & 63;
  int l15 = lane & 15, lg = lane >> 4;
  int n0 = blockIdx.x * 64;
  short8v sv[8];
#pragma unroll
  for (int u = 0; u < 8; ++u) {
    int idx = u * 256 + tid;
    int row = idx >> 5, q = idx & 31;
    int n = min(n0 + row, NN - 1);
    sv[u] = *(const short8v*)(featb + (size_t)n * 256 + q * 8);
  }
#pragma unroll
  for (int u = 0; u < 8; ++u) {
    int idx = u * 256 + tid;
    int row = idx >> 5, q = idx & 31;
    *(short8v*)(lA + ((row * 512 + q * 16) ^ ((row & 7) << 4))) = sv[u];
  }
  __syncthreads();
  f32x4 acc[4][4];
#pragma unroll
  for (int m = 0; m < 4; ++m)
#pragma unroll
    for (int c = 0; c < 4; ++c) acc[m][c] = (f32x4){0.f, 0.f, 0.f, 0.f};
  const short* bp = spk + (size_t)wave * 4 * 4096 + (size_t)lane * 8;
#pragma unroll
  for (int kt = 0; kt < 8; ++kt) {
    short8v a[4], b[4];
#pragma unroll
    for (int c = 0; c < 4; ++c) b[c] = *(const short8v*)(bp + c * 4096 + kt * 512);
#pragma unroll
    for (int m = 0; m < 4; ++m) {
      int row = m * 16 + l15;
      a[m] = *(const short8v*)(lA + ((row * 512 + kt * 64 + lg * 16) ^ ((row & 7) << 4)));
    }
#pragma unroll
    for (int m = 0; m < 4; ++m)
#pragma unroll
      for (int c = 0; c < 4; ++c)
        acc[m][c] = __builtin_amdgcn_mfma_f32_16x16x32_bf16(a[m], b[c], acc[m][c], 0, 0, 0);
  }
#pragma unroll
  for (int m = 0; m < 4; ++m)
#pragma unroll
    for (int j = 0; j < 4; ++j) {
      int n = n0 + m * 16 + lg * 4 + j;
      if (n < NN) {
        float* op = out + (size_t)n * 256 + wave * 64 + l15;
#pragma unroll
        for (int c = 0; c < 4; ++c) op[c * 16] = acc[m][c][j];
      }
    }
}

// ---------------------------------------------------------------------------
// Tier A aggregate: LDS-free; one 16-lane group per dst node. msg rows are
// pre-scaled -> plain sum; RMW of out (holds self-loop term).
__global__ __launch_bounds__(256) void k_aggregate(
    const unsigned short* __restrict__ msg, const int* __restrict__ row_ptr,
    const int* __restrict__ dlist, float* __restrict__ out) {
  int g = blockIdx.x * 16 + (threadIdx.x >> 4);
  if (g >= NN) return;
  int gl = threadIdx.x & 15;
  int gw = (threadIdx.x >> 4) & 3;           // group index within wave
  int lo = row_ptr[g], hi = row_ptr[g + 1];
  if (lo >= hi) return;
  float a[16];
#pragma unroll
  for (int k = 0; k < 16; ++k) a[k] = 0.f;
  for (int q0 = lo; q0 < hi; q0 += 16) {
    int pv = (q0 + gl < hi) ? dlist[q0 + gl] : 0;
    int qm = min(16, hi - q0);
    for (int j = 0; j < qm; ++j) {
      int p = __shfl(pv, gw * 16 + j, 64);
      const unsigned short* mp = msg + (size_t)p * 256 + gl * 16;
      short8v m0 = *(const short8v*)mp;
      short8v m1 = *(const short8v*)(mp + 8);
#pragma unroll
      for (int k = 0; k < 8; ++k) {
        a[k]     += bf2f((unsigned short)m0[k]);
        a[k + 8] += bf2f((unsigned short)m1[k]);
      }
    }
  }
  float* op = out + (size_t)g * 256 + gl * 16;
#pragma unroll
  for (int c = 0; c < 4; ++c) {
    f32x4 o = *(const f32x4*)(op + c * 4);
    o[0] += a[c * 4]; o[1] += a[c * 4 + 1]; o[2] += a[c * 4 + 2]; o[3] += a[c * 4 + 3];
    *(f32x4*)(op + c * 4) = o;
  }
}

// ---------------------------------------------------------------------------
// Tier B/C fallbacks (atomic epilogue), using flat gsrc/gdst/ginv metadata.
__device__ __forceinline__ void gemm64(const char* lA, const short* __restrict__ wpk,
                                       f32x4 acc[4][4], int wave, int lane) {
  int l15 = lane & 15, lg = lane >> 4;
  const short* bp = wpk + (size_t)wave * 4 * 4096 + (size_t)lane * 8;
#pragma unroll
  for (int kt = 0; kt < 8; ++kt) {
    short8v a[4], b[4];
#pragma unroll
    for (int c = 0; c < 4; ++c) b[c] = *(const short8v*)(bp + c * 4096 + kt * 512);
#pragma unroll
    for (int m = 0; m < 4; ++m) {
      int row = m * 16 + l15;
      a[m] = *(const short8v*)(lA + ((row * 512 + kt * 64 + lg * 16) ^ ((row & 7) << 4)));
    }
#pragma unroll
    for (int m = 0; m < 4; ++m)
#pragma unroll
      for (int c = 0; c < 4; ++c)
        acc[m][c] = __builtin_amdgcn_mfma_f32_16x16x32_bf16(a[m], b[c], acc[m][c], 0, 0, 0);
  }
}

template <bool B16>
__global__ __launch_bounds__(256) void k_self_gemm(const float* __restrict__ in_feat,
                                                   const unsigned short* __restrict__ featb,
                                                   const short* __restrict__ spk,
                                                   float* __restrict__ out) {
  __shared__ __align__(16) char lA[32768];
  int n0 = blockIdx.x * 64;
  int tid = threadIdx.x;
  if (B16) {
    short8v sv[8];
#pragma unroll
    for (int u = 0; u < 8; ++u) {
      int idx = u * 256 + tid;
      int row = idx >> 5, q = idx & 31;
      int n = min(n0 + row, NN - 1);
      sv[u] = *(const short8v*)(featb + (size_t)n * 256 + q * 8);
    }
#pragma unroll
    for (int u = 0; u < 8; ++u) {
      int idx = u * 256 + tid;
      int row = idx >> 5, q = idx & 31;
      *(short8v*)(lA + ((row * 512 + q * 16) ^ ((row & 7) << 4))) = sv[u];
    }
  } else {
#pragma unroll
    for (int half = 0; half < 2; ++half) {
      float4 v[8];
#pragma unroll
      for (int u = 0; u < 8; ++u) {
        int it = half * 2048 + u * 256 + tid;
        int row = it >> 6, q = it & 63;
        int n = n0 + row;
        v[u] = (n < NN) ? ((const float4*)(in_feat + (size_t)n * 256))[q]
                        : make_float4(0.f, 0.f, 0.f, 0.f);
      }
#pragma unroll
      for (int u = 0; u < 8; ++u) {
        int it = half * 2048 + u * 256 + tid;
        int row = it >> 6, q = it & 63;
        ushort4 hh;
        hh.x = f2bf(v[u].x); hh.y = f2bf(v[u].y); hh.z = f2bf(v[u].z); hh.w = f2bf(v[u].w);
        *(ushort4*)(lA + ((row * 512 + q * 8) ^ ((row & 7) << 4))) = hh;
      }
    }
  }
  __syncthreads();
  f32x4 acc[4][4];
#pragma unroll
  for (int m = 0; m < 4; ++m)
#pragma unroll
    for (int c = 0; c < 4; ++c) acc[m][c] = (f32x4){0.f, 0.f, 0.f, 0.f};
  int wave = tid >> 6, lane = tid & 63;
  gemm64(lA, spk, acc, wave, lane);
  int l15 = lane & 15, lg = lane >> 4;
#pragma unroll
  for (int m = 0; m < 4; ++m)
#pragma unroll
    for (int j = 0; j < 4; ++j) {
      int n = n0 + m * 16 + lg * 4 + j;
      if (n < NN) {
        float* op = out + (size_t)n * 256 + wave * 64 + l15;
#pragma unroll
        for (int c = 0; c < 4; ++c) op[c * 16] = acc[m][c][j];
      }
    }
}

template <int MODE>   // 0: f32 feat, 1: bf16 feat; atomic mean-scatter into out
__global__ __launch_bounds__(256) void k_edge_gemmBC(const float* __restrict__ in_feat,
                                                     const unsigned short* __restrict__ featb,
                                                     const short* __restrict__ wpk,
                                                     const int* __restrict__ gsrc,
                                                     const int* __restrict__ gdst,
                                                     const float* __restrict__ ginv,
                                                     const int4* __restrict__ tdesc,
                                                     float* __restrict__ out) {
  __shared__ __align__(16) char lA[32768];
  __shared__ int lsrc[64];
  __shared__ int ldst[64];
  __shared__ float linv[64];
  int bid = blockIdx.x;
  int tile = (bid & 7) * (MAXTILES / 8) + (bid >> 3);
  int4 d = tdesc[tile];
  int rows = d.z;
  if (rows <= 0) return;
  int r = d.x, rs = d.y;
  int tid = threadIdx.x;
  if (tid < 64) {
    if (tid < rows) {
      lsrc[tid] = gsrc[rs + tid];
      ldst[tid] = gdst[rs + tid];
      linv[tid] = ginv[rs + tid];
    } else {
      lsrc[tid] = -1; ldst[tid] = -1; linv[tid] = 0.f;
    }
  }
  __syncthreads();
  if (MODE == 1) {
    short8v sv[8];
#pragma unroll
    for (int u = 0; u < 8; ++u) {
      int idx = u * 256 + tid;
      int row = idx >> 5, q = idx & 31;
      int s = lsrc[row];
      sv[u] = (s >= 0) ? *(const short8v*)(featb + (size_t)s * 256 + q * 8)
                       : (short8v){0, 0, 0, 0, 0, 0, 0, 0};
    }
#pragma unroll
    for (int u = 0; u < 8; ++u) {
      int idx = u * 256 + tid;
      int row = idx >> 5, q = idx & 31;
      *(short8v*)(lA + ((row * 512 + q * 16) ^ ((row & 7) << 4))) = sv[u];
    }
  } else {
#pragma unroll
    for (int half = 0; half < 2; ++half) {
      float4 v[8];
#pragma unroll
      for (int u = 0; u < 8; ++u) {
        int it = half * 2048 + u * 256 + tid;
        int row = it >> 6, q = it & 63;
        int s = lsrc[row];
        v[u] = (s >= 0) ? ((const float4*)(in_feat + (size_t)s * 256))[q]
                        : make_float4(0.f, 0.f, 0.f, 0.f);
      }
#pragma unroll
      for (int u = 0; u < 8; ++u) {
        int it = half * 2048 + u * 256 + tid;
        int row = it >> 6, q = it & 63;
        ushort4 hh;
        hh.x = f2bf(v[u].x); hh.y = f2bf(v[u].y); hh.z = f2bf(v[u].z); hh.w = f2bf(v[u].w);
        *(ushort4*)(lA + ((row * 512 + q * 8) ^ ((row & 7) << 4))) = hh;
      }
    }
  }
  __syncthreads();
  f32x4 acc[4][4];
#pragma unroll
  for (int m = 0; m < 4; ++m)
#pragma unroll
    for (int c = 0; c < 4; ++c) acc[m][c] = (f32x4){0.f, 0.f, 0.f, 0.f};
  int wave = tid >> 6, lane = tid & 63;
  gemm64(lA, wpk + (size_t)r * 65536, acc, wave, lane);
  int l15 = lane & 15, lg = lane >> 4;
#pragma unroll
  for (int m = 0; m < 4; ++m)
#pragma unroll
    for (int j = 0; j < 4; ++j) {
      int row = m * 16 + lg * 4 + j;
      int dd = ldst[row];
      if (dd >= 0) {
        float inv = linv[row];
        float* op = out + (size_t)dd * 256 + wave * 64 + l15;
#pragma unroll
        for (int c = 0; c < 4; ++c) unsafeAtomicAdd(op + c * 16, acc[m][c][j] * inv);
      }
    }
}

// ---------------------------------------------------------------------------
extern "C" void kernel_launch(void* const* d_in, const int* in_sizes, int n_in,
                              void* d_out, int out_size, void* d_ws, size_t ws_size,
                              hipStream_t stream) {
  const float* in_feat = (const float*)d_in[0];
  const float* basis   = (const float*)d_in[1];
  const float* coef    = (const float*)d_in[2];
  const float* slw     = (const float*)d_in[3];
  const int*   src     = (const int*)d_in[4];
  const int*   dst     = (const int*)d_in[5];
  const int*   etype   = (const int*)d_in[6];
  float* out = (float*)d_out;

  char* base = (char*)d_ws;
  char* w = base;
  auto alloc = [&](size_t bytes) {
    char* p = w;
    w += (bytes + 255) & ~(size_t)255;
    return p;
  };
  // base group (tiers B/C)
  short* wpk  = (short*)alloc((size_t)RR * 65536 * 2);   // 26.2 MB
  short* spk  = (short*)alloc(65536 * 2);
  int*   gsrc = (int*)alloc((size_t)EE * 4);
  int*   gdst = (int*)alloc((size_t)EE * 4);
  float* ginv = (float*)alloc((size_t)EE * 4);
  int*   deg  = (int*)alloc((size_t)NN * 4);
  int*   hist = (int*)alloc(RR * 4);
  int*   cur  = (int*)alloc(RR * 4);
  int4*  tdesc = (int4*)alloc((size_t)MAXTILES * 16);
  int*   bsum = (int*)alloc(NSCAN * 4);
  // tier B adds bf16 feat
  unsigned short* featb = (unsigned short*)alloc((size_t)NN * 256 * 2);  // 51.2 MB
  size_t need_b = (size_t)(w - base);
  // tier A adds dst-CSR + msg buffer
  int* row_ptr = (int*)alloc((size_t)(NN + 1) * 4);
  int* cur2    = (int*)alloc((size_t)NN * 4);
  int* dlist   = (int*)alloc((size_t)EE * 4);
  unsigned short* msg = (unsigned short*)alloc((size_t)EE * 256 * 2);    // 204.8 MB
  size_t need_a = (size_t)(w - base);

  bool tierA = ws_size >= need_a;
  bool tierB = ws_size >= need_b;

  hipMemsetAsync(hist, 0, RR * 4, stream);
  hipMemsetAsync(deg, 0, (size_t)NN * 4, stream);

  if (tierA) {
    k_prep1<true><<<1344, 256, 0, stream>>>(basis, coef, slw, etype, dst, in_feat,
                                            wpk, spk, hist, deg, featb);
    k_prep2<<<NSCAN + 1, 256, 0, stream>>>(hist, deg, cur, tdesc, bsum);
    k_prep3<<<NSCAN, 256, 0, stream>>>(deg, bsum, row_ptr, cur2);
    k_prep4<true><<<(EE + SCHUNK - 1) / SCHUNK, 256, 0, stream>>>(
        etype, src, dst, deg, cur, gsrc, gdst, ginv, cur2, dlist);
    k_selfA<<<(NN + 63) / 64, 256, 0, stream>>>(featb, spk, out);
    k_edge<<<EGRID, 512, 0, stream>>>(featb, wpk, gsrc, ginv, tdesc, msg);
    k_aggregate<<<(NN + 15) / 16, 256, 0, stream>>>(msg, row_ptr, dlist, out);
  } else if (tierB) {
    k_prep1<true><<<1344, 256, 0, stream>>>(basis, coef, slw, etype, dst, in_feat,
                                            wpk, spk, hist, deg, featb);
    k_prep2<<<NSCAN + 1, 256, 0, stream>>>(hist, deg, cur, tdesc, bsum);
    k_prep4<false><<<(EE + SCHUNK - 1) / SCHUNK, 256, 0, stream>>>(
        etype, src, dst, deg, cur, gsrc, gdst, ginv, nullptr, nullptr);
    k_self_gemm<true><<<(NN + 63) / 64, 256, 0, stream>>>(in_feat, featb, spk, out);
    k_edge_gemmBC<1><<<MAXTILES, 256, 0, stream>>>(in_feat, featb, wpk, gsrc, gdst,
                                                   ginv, tdesc, out);
  } else {
    k_prep1<false><<<1344, 256, 0, stream>>>(basis, coef, slw, etype, dst, in_feat,
                                             wpk, spk, hist, deg, nullptr);
    k_prep2<<<NSCAN + 1, 256, 0, stream>>>(hist, deg, cur, tdesc, bsum);
    k_prep4<false><<<(EE + SCHUNK - 1) / SCHUNK, 256, 0, stream>>>(
        etype, src, dst, deg, cur, gsrc, gdst, ginv, nullptr, nullptr);
    k_self_gemm<false><<<(NN + 63) / 64, 256, 0, stream>>>(in_feat, nullptr, spk, out);
    k_edge_gemmBC<0><<<MAXTILES, 256, 0, stream>>>(in_feat, nullptr, wpk, gsrc, gdst,
                                                   ginv, tdesc, out);
  }
}